// Round 17
// baseline (115.157 us; speedup 1.0000x reference)
//
#include <hip/hip_runtime.h>

// ---------- types ----------
using bh8    = __attribute__((ext_vector_type(8)))  short;          // 8 bf16 (4 VGPR)
using f32x4v = __attribute__((ext_vector_type(4)))  float;
using f32x16 = __attribute__((ext_vector_type(16))) float;
using u32x4  = __attribute__((ext_vector_type(4)))  unsigned int;
using us4    = __attribute__((ext_vector_type(4)))  unsigned short;

#define AS1 __attribute__((address_space(1)))
#define AS3 __attribute__((address_space(3)))

#define B_  2
#define S_  2048
#define D_  1024
#define H_  16
#define HD_ 64
#define C2A 0.0360673760222241f   // 0.2/sqrt(64) * log2(e), folded into Q

__device__ __forceinline__ unsigned short f2bf(float f) {
  unsigned u = __builtin_bit_cast(unsigned, f);
  return (unsigned short)((u + 0x7fffu + ((u >> 16) & 1u)) >> 16);   // RNE
}
__device__ __forceinline__ float bf2f(unsigned short v) {
  return __builtin_bit_cast(float, (unsigned)v << 16);
}
__device__ __forceinline__ int swz8(int r) { return (r ^ (r >> 3)) & 7; }

// ---------- fused f32 -> bf16 convert, grid-strided (2048 blocks x 4 iters) ----------
__global__ __launch_bounds__(256) void cvt_all(const float* __restrict__ x,
                                               const float* __restrict__ qw,
                                               const float* __restrict__ ow,
                                               unsigned short* __restrict__ xb,
                                               unsigned short* __restrict__ qwb,
                                               unsigned short* __restrict__ owb) {
#pragma unroll
  for (int it = 0; it < 4; it++) {
    int i = it * 524288 + blockIdx.x * 256 + threadIdx.x;  // vec4 index over 8M floats
    const float* src; unsigned short* dst; int off;
    if (i < 1048576)      { src = x;  dst = xb;  off = i; }
    else if (i < 1835008) { src = qw; dst = qwb; off = i - 1048576; }
    else                  { src = ow; dst = owb; off = i - 1835008; }
    f32x4v v = reinterpret_cast<const f32x4v*>(src)[off];
    us4 o;
    o[0] = f2bf(v[0]); o[1] = f2bf(v[1]); o[2] = f2bf(v[2]); o[3] = f2bf(v[3]);
    reinterpret_cast<us4*>(dst)[off] = o;
  }
}

// ---------- GEMM: C[m,e] = sum_k A[m,k]*B[e,k] (+bias) ----------
// MODE 0: scatter bf16: Q (scaled by C2A) [bh][s][64], K [bh][s][64], V^T [bh][d][S]
// MODE 1: f32 out C[m*N+e] (+bias)
// BM: 128 (waves 2x2, acc[4][4]) or 64 (waves 1x4, acc[4][2])
// GX = gridDim.x, NW = total blocks (both %8 == 0) for bijective XCD swizzle (T1)
template <int MODE, int BM, int GX, int NW>
__global__ __launch_bounds__(256) void gemm_bt(const unsigned short* __restrict__ A,
                                               const unsigned short* __restrict__ Bw,
                                               const float* __restrict__ bias,
                                               float* __restrict__ Cf,
                                               unsigned short* __restrict__ Qo,
                                               unsigned short* __restrict__ Ko,
                                               unsigned short* __restrict__ Vo,
                                               int M, int N, int K) {
  constexpr int NIW = (BM == 128) ? 4 : 2;     // n-frags per wave
  constexpr int NA  = BM / 32;                 // A-staging issues: 256thr*16B = 4KB = 32 rows
  __shared__ __align__(16) short As[BM * 64];
  __shared__ __align__(16) short Bs[128 * 64];
  const int tid = threadIdx.x;
  const int w = tid >> 6, l = tid & 63;
  const int lr = l & 15, lg = l >> 4;
  // XCD swizzle: bijective since NW % 8 == 0
  const int lin = blockIdx.y * GX + blockIdx.x;
  const int sw  = (lin & 7) * (NW / 8) + (lin >> 3);
  const int m0 = (sw % GX) * BM, n0 = (sw / GX) * 128;
  const int wm = (BM == 128) ? (w >> 1) * 64 : 0;
  const int wn = (BM == 128) ? (w & 1) * 64 : w * 32;

  f32x4v acc[4][NIW];
#pragma unroll
  for (int a = 0; a < 4; a++)
#pragma unroll
    for (int b = 0; b < NIW; b++)
#pragma unroll
      for (int r = 0; r < 4; r++) acc[a][b][r] = 0.f;

#pragma unroll 1
  for (int k0 = 0; k0 < K; k0 += 64) {
    __syncthreads();
#pragma unroll
    for (int n = 0; n < NA; n++) {
      int idx = n * 256 + tid;
      int row = idx >> 3, p = idx & 7;
      int c = p ^ swz8(row);
      const unsigned short* srcA = A + (size_t)(m0 + row) * K + k0 + c * 8;
      __builtin_amdgcn_global_load_lds((const AS1 void*)srcA,
          (AS3 void*)((char*)As + (n * 256 + w * 64) * 16), 16, 0, 0);
    }
#pragma unroll
    for (int n = 0; n < 4; n++) {
      int idx = n * 256 + tid;
      int row = idx >> 3, p = idx & 7;
      int c = p ^ swz8(row);
      const unsigned short* srcB = Bw + (size_t)(n0 + row) * K + k0 + c * 8;
      __builtin_amdgcn_global_load_lds((const AS1 void*)srcB,
          (AS3 void*)((char*)Bs + (n * 256 + w * 64) * 16), 16, 0, 0);
    }
    __syncthreads();
#pragma unroll
    for (int kk = 0; kk < 2; kk++) {
      bh8 af[4], bf[NIW];
#pragma unroll
      for (int mi = 0; mi < 4; mi++) {
        int row = wm + mi * 16 + lr;
        int slot = (4 * kk + lg) ^ swz8(row);
        af[mi] = *(const bh8*)((const char*)As + row * 128 + slot * 16);
      }
#pragma unroll
      for (int ni = 0; ni < NIW; ni++) {
        int row = wn + ni * 16 + lr;
        int slot = (4 * kk + lg) ^ swz8(row);
        bf[ni] = *(const bh8*)((const char*)Bs + row * 128 + slot * 16);
      }
#pragma unroll
      for (int mi = 0; mi < 4; mi++)
#pragma unroll
        for (int ni = 0; ni < NIW; ni++)
          acc[mi][ni] = __builtin_amdgcn_mfma_f32_16x16x32_bf16(af[mi], bf[ni], acc[mi][ni], 0, 0, 0);
    }
  }

  // D layout (16x16): col=e=lane&15, row=m=(lane>>4)*4+r  [m89]
  if (MODE == 1) {
#pragma unroll
    for (int ni = 0; ni < NIW; ni++) {
      int e = n0 + wn + ni * 16 + lr;
      float bv = bias[e];
#pragma unroll
      for (int mi = 0; mi < 4; mi++) {
        int mbase = m0 + wm + mi * 16 + lg * 4;
#pragma unroll
        for (int r = 0; r < 4; r++)
          Cf[(size_t)(mbase + r) * N + e] = acc[mi][ni][r] + bv;
      }
    }
  } else {
#pragma unroll
    for (int ni = 0; ni < NIW; ni++) {
      int e = n0 + wn + ni * 16 + lr;
      int hh = e / 192;
      int rr = e - hh * 192;
      int tsel = rr >> 6, d = rr & 63;
      float bv = bias[e];
#pragma unroll
      for (int mi = 0; mi < 4; mi++) {
        int mbase = m0 + wm + mi * 16 + lg * 4;
#pragma unroll
        for (int r = 0; r < 4; r++) {
          int m = mbase + r;
          int b = m >> 11, s = m & 2047;
          float val = acc[mi][ni][r] + bv;
          size_t bh = (size_t)(b * H_ + hh);
          if (tsel == 0)      Qo[(bh * S_ + s) * HD_ + d] = f2bf(val * C2A);
          else if (tsel == 1) Ko[(bh * S_ + s) * HD_ + d] = f2bf(val);
          else                Vo[(bh * HD_ + d) * S_ + s] = f2bf(val);   // V^T
        }
      }
    }
  }
}

// ---------- fused attention, cross-block t-split (R10-verified 64KB body) ----------
// grid 512 (XCD-swizzled), 512 thr = 8 waves, 2 blocks/CU -> 16 waves/CU.
// Block (bh, q-block, part): part p handles t in [1024p, 1024p+1024).
// Writes UN-normalized partial O (bf16) to Po[part] and partial L (f32).
// Per-block sync structure identical to R10 (vmcnt0+barrier, 128-t per iter).
__global__ __launch_bounds__(512) void attn_fwd(const unsigned short* __restrict__ Qt,
                                                const unsigned short* __restrict__ Kt,
                                                const unsigned short* __restrict__ VT,
                                                unsigned short* __restrict__ P0,
                                                unsigned short* __restrict__ P1,
                                                float* __restrict__ Lp) {
  __shared__ __align__(16) short Ks[2 * 2 * 64 * 64];   // [buf][tile][64][64] 32KB
  __shared__ __align__(16) short Vs[2 * 2 * 64 * 64];   // 32KB
  const int tid = threadIdx.x, w = tid >> 6, l = tid & 63;
  const int lq = l & 31, h = l >> 5;
  // decode: XCD-grouped by bh (lin%8); rest -> q-block and t-part
  const int lin = blockIdx.x;
  const int uu_ = lin >> 3;
  const int bh = (lin & 7) + 8 * (uu_ & 3);
  const int rest = uu_ >> 2;                 // 0..15
  const int q0 = (rest >> 1) * 256 + w * 32;
  const int part = rest & 1;
  const int tbase = part * 1024;
  const unsigned short* Qp = Qt + (size_t)bh * (S_ * HD_);
  const unsigned short* Kp = Kt + (size_t)bh * (S_ * HD_);
  const unsigned short* Vp = VT + (size_t)bh * (HD_ * S_);

  bh8 qf[4];  // B-frags: col=q=lane&31, k=d=(lane>>5)*8+j
#pragma unroll
  for (int kf = 0; kf < 4; kf++)
    qf[kf] = *(const bh8*)(Qp + (size_t)(q0 + lq) * HD_ + kf * 16 + h * 8);

  f32x16 KZ;
#pragma unroll
  for (int r = 0; r < 16; r++) KZ[r] = 0.f;
  bh8 ones;
#pragma unroll
  for (int j = 0; j < 8; j++) ones[j] = (short)0x3F80;

  f32x16 O[2], Ol;
  O[0] = KZ; O[1] = KZ; Ol = KZ;

  // per-thread staging addresses (512 threads cover one 64x64 tile per issue)
  const int row0 = tid >> 3, cc = (tid & 7) ^ swz8(row0);
  const unsigned short* kp0 = Kp + (size_t)(tbase + row0) * HD_ + cc * 8;
  const unsigned short* vp0 = Vp + (size_t)row0 * S_ + tbase + cc * 8;
  char* dK = (char*)Ks + w * 1024;
  char* dV = (char*)Vs + w * 1024;

  // i indexes 128-t super-tiles within this part; tiles at t = tbase + 128i (+64)
  auto stage = [&](int i, int buf) {
    const unsigned short* kB = kp0 + (size_t)i * 8192;   // 128 rows * 64 elems
    const unsigned short* vB = vp0 + (size_t)i * 128;    // V^T: +128 t-elems
    __builtin_amdgcn_global_load_lds((const AS1 void*)kB,
                                     (AS3 void*)(dK + buf * 16384), 16, 0, 0);
    __builtin_amdgcn_global_load_lds((const AS1 void*)(kB + 4096),
                                     (AS3 void*)(dK + buf * 16384 + 8192), 16, 0, 0);
    __builtin_amdgcn_global_load_lds((const AS1 void*)vB,
                                     (AS3 void*)(dV + buf * 16384), 16, 0, 0);
    __builtin_amdgcn_global_load_lds((const AS1 void*)(vB + 64),
                                     (AS3 void*)(dV + buf * 16384 + 8192), 16, 0, 0);
  };

  // LDS read byte-offsets within a 64x64 tile (loop-invariant)
  int ko0[4], ko1[4], vo0[4], vo1[4];
#pragma unroll
  for (int kf = 0; kf < 4; kf++) {
    int r0 = lq, r1 = 32 + lq;
    ko0[kf] = r0 * 128 + (((2 * kf + h) ^ swz8(r0)) << 4);
    ko1[kf] = r1 * 128 + (((2 * kf + h) ^ swz8(r1)) << 4);
  }
#pragma unroll
  for (int c = 0; c < 2; c++)
#pragma unroll
    for (int ni = 0; ni < 2; ni++) {
      int d = ni * 32 + lq;
      vo0[c * 2 + ni] = d * 128 + (((2 * c + h) ^ swz8(d)) << 4);
      vo1[c * 2 + ni] = d * 128 + (((4 + 2 * c + h) ^ swz8(d)) << 4);
    }

  stage(0, 0);
#pragma unroll 1
  for (int i = 0; i < 8; i++) {
    const int cur = i & 1;
    asm volatile("s_waitcnt vmcnt(0)" ::: "memory");   // my tile-i staging done
    __builtin_amdgcn_s_barrier();                      // everyone staged; prev-buf readers done
    if (i < 7) stage(i + 1, cur ^ 1);                  // prefetch flies under compute
#pragma unroll
    for (int tt = 0; tt < 2; tt++) {
      const char* Kc = (const char*)Ks + cur * 16384 + tt * 8192;
      const char* Vc = (const char*)Vs + cur * 16384 + tt * 8192;

      // ---- QK^T, both 32-t sub-tiles ----
      f32x16 sa, sb;
      __builtin_amdgcn_s_setprio(1);
      {
        bh8 k0 = *(const bh8*)(Kc + ko0[0]);
        bh8 k1 = *(const bh8*)(Kc + ko1[0]);
        sa = __builtin_amdgcn_mfma_f32_32x32x16_bf16(k0, qf[0], KZ, 0, 0, 0);
        sb = __builtin_amdgcn_mfma_f32_32x32x16_bf16(k1, qf[0], KZ, 0, 0, 0);
      }
#pragma unroll
      for (int kf = 1; kf < 4; kf++) {
        bh8 k0 = *(const bh8*)(Kc + ko0[kf]);
        bh8 k1 = *(const bh8*)(Kc + ko1[kf]);
        sa = __builtin_amdgcn_mfma_f32_32x32x16_bf16(k0, qf[kf], sa, 0, 0, 0);
        sb = __builtin_amdgcn_mfma_f32_32x32x16_bf16(k1, qf[kf], sb, 0, 0, 0);
      }
      __builtin_amdgcn_s_setprio(0);

      // ---- softmax numerators, chain a then chain b ----
      float pa_[16], pb_[16];
#pragma unroll
      for (int r = 0; r < 16; r++)
        asm("v_exp_f32 %0, %1" : "=v"(pa_[r]) : "v"(sa[r]));
      unsigned wa0[4], wa1[4];
#pragma unroll
      for (int g = 0; g < 4; g++) {
        asm("v_cvt_pk_bf16_f32 %0, %1, %2" : "=v"(wa0[g]) : "v"(pa_[4 * g]), "v"(pa_[4 * g + 1]));
        asm("v_cvt_pk_bf16_f32 %0, %1, %2" : "=v"(wa1[g]) : "v"(pa_[4 * g + 2]), "v"(pa_[4 * g + 3]));
      }
#pragma unroll
      for (int r = 0; r < 16; r++)
        asm("v_exp_f32 %0, %1" : "=v"(pb_[r]) : "v"(sb[r]));
      unsigned wb0[4], wb1[4];
#pragma unroll
      for (int g = 0; g < 4; g++) {
        asm("v_cvt_pk_bf16_f32 %0, %1, %2" : "=v"(wb0[g]) : "v"(pb_[4 * g]), "v"(pb_[4 * g + 1]));
        asm("v_cvt_pk_bf16_f32 %0, %1, %2" : "=v"(wb1[g]) : "v"(pb_[4 * g + 2]), "v"(pb_[4 * g + 3]));
      }

      // ---- rebuild PV A-frags via permlane32_swap (T12) ----
      bh8 paf[2], pbf[2];
#pragma unroll
      for (int c = 0; c < 2; c++) {
        unsigned x0 = wa0[2 * c], y0 = wa0[2 * c + 1];
        unsigned x1 = wa1[2 * c], y1 = wa1[2 * c + 1];
        asm("v_permlane32_swap_b32 %0, %1" : "+v"(x0), "+v"(y0));
        asm("v_permlane32_swap_b32 %0, %1" : "+v"(x1), "+v"(y1));
        u32x4 up; up[0] = x0; up[1] = x1; up[2] = y0; up[3] = y1;
        paf[c] = __builtin_bit_cast(bh8, up);
      }
#pragma unroll
      for (int c = 0; c < 2; c++) {
        unsigned x0 = wb0[2 * c], y0 = wb0[2 * c + 1];
        unsigned x1 = wb1[2 * c], y1 = wb1[2 * c + 1];
        asm("v_permlane32_swap_b32 %0, %1" : "+v"(x0), "+v"(y0));
        asm("v_permlane32_swap_b32 %0, %1" : "+v"(x1), "+v"(y1));
        u32x4 up; up[0] = x0; up[1] = x1; up[2] = y0; up[3] = y1;
        pbf[c] = __builtin_bit_cast(bh8, up);
      }

      // ---- PV + L, both chains ----
      __builtin_amdgcn_s_setprio(1);
#pragma unroll
      for (int c = 0; c < 2; c++) {
        bh8 vf0 = *(const bh8*)(Vc + vo0[c * 2 + 0]);
        bh8 vf1 = *(const bh8*)(Vc + vo0[c * 2 + 1]);
        O[0] = __builtin_amdgcn_mfma_f32_32x32x16_bf16(paf[c], vf0, O[0], 0, 0, 0);
        O[1] = __builtin_amdgcn_mfma_f32_32x32x16_bf16(paf[c], vf1, O[1], 0, 0, 0);
        Ol   = __builtin_amdgcn_mfma_f32_32x32x16_bf16(paf[c], ones, Ol, 0, 0, 0);
      }
#pragma unroll
      for (int c = 0; c < 2; c++) {
        bh8 vf0 = *(const bh8*)(Vc + vo1[c * 2 + 0]);
        bh8 vf1 = *(const bh8*)(Vc + vo1[c * 2 + 1]);
        O[0] = __builtin_amdgcn_mfma_f32_32x32x16_bf16(pbf[c], vf0, O[0], 0, 0, 0);
        O[1] = __builtin_amdgcn_mfma_f32_32x32x16_bf16(pbf[c], vf1, O[1], 0, 0, 0);
        Ol   = __builtin_amdgcn_mfma_f32_32x32x16_bf16(pbf[c], ones, Ol, 0, 0, 0);
      }
      __builtin_amdgcn_s_setprio(0);
    }
  }

  // ---- write UN-normalized partial O (bf16) + partial L (f32) ----
  unsigned short* po = part ? P1 : P0;
  const int b = bh >> 4, hh = bh & 15;
#pragma unroll
  for (int ni = 0; ni < 2; ni++) {
    int d = ni * 32 + lq;
#pragma unroll
    for (int r = 0; r < 16; r++) {
      int qg = q0 + 4 * h + 8 * (r >> 2) + (r & 3);
      po[((size_t)(b * S_ + qg)) * D_ + hh * HD_ + d] = f2bf(O[ni][r]);
    }
  }
  if (lq == 0) {     // 2 lanes/wave (h=0,1) each own 16 q-rows' L
#pragma unroll
    for (int r = 0; r < 16; r++) {
      int qg = q0 + 4 * h + 8 * (r >> 2) + (r & 3);
      Lp[part * 65536 + bh * 2048 + qg] = Ol[r];
    }
  }
}

// ---------- combine: out = (P0 + P1) / (L0 + L1), in-place into P0 ----------
__global__ __launch_bounds__(256) void combine(const unsigned short* __restrict__ P1,
                                               const float* __restrict__ Lp,
                                               unsigned short* __restrict__ P0out) {
  int i = blockIdx.x * 256 + threadIdx.x;        // vec4 index, 1048576 total
  int e4 = i << 2;
  int hhd = e4 & 1023;                           // hh*64+d
  int s   = (e4 >> 10) & 2047;
  int b   = e4 >> 21;
  int hh  = hhd >> 6;
  int li  = (b * H_ + hh) * S_ + s;
  float rl = __builtin_amdgcn_rcpf(Lp[li] + Lp[65536 + li]);
  us4 a = reinterpret_cast<const us4*>(P0out)[i];
  us4 c = reinterpret_cast<const us4*>(P1)[i];
  us4 o;
#pragma unroll
  for (int j = 0; j < 4; j++)
    o[j] = f2bf((bf2f(a[j]) + bf2f(c[j])) * rl);
  reinterpret_cast<us4*>(P0out)[i] = o;
}

// ---------- launch ----------
extern "C" void kernel_launch(void* const* d_in, const int* in_sizes, int n_in,
                              void* d_out, int out_size, void* d_ws, size_t ws_size,
                              hipStream_t stream) {
  const float* x     = (const float*)d_in[0];
  const float* qkv_w = (const float*)d_in[1];
  const float* qkv_b = (const float*)d_in[2];
  const float* out_w = (const float*)d_in[3];
  const float* out_b = (const float*)d_in[4];
  float* out = (float*)d_out;

  unsigned short* xb  = (unsigned short*)d_ws;                 // 8 MB  x bf16; REUSED: attn P1
  unsigned short* qwb = xb  + (size_t)4096 * 1024;             // 6 MB  qkv_w bf16; REUSED: L partials
  unsigned short* owb = qwb + (size_t)3072 * 1024;             // 2 MB  out_w bf16 (live until gemm1)
  unsigned short* Qb  = owb + (size_t)1024 * 1024;             // 8 MB  Q*C2 [32][2048][64]
  unsigned short* Kb  = Qb  + (size_t)32 * 2048 * 64;          // 8 MB  K [32][2048][64]
  unsigned short* Vb  = Kb  + (size_t)32 * 2048 * 64;          // 8 MB  V^T [32][64][2048]
  unsigned short* vb  = Vb  + (size_t)32 * 2048 * 64;          // 8 MB  attn P0 / combined vals

  cvt_all<<<2048, 256, 0, stream>>>(x, qkv_w, out_w, xb, qwb, owb);
  gemm_bt<0, 128, 32, 768><<<dim3(32, 24), 256, 0, stream>>>(xb, qwb, qkv_b, nullptr, Qb, Kb, Vb,
                                                             4096, 3072, 1024);
  attn_fwd<<<512, 512, 0, stream>>>(Qb, Kb, Vb, vb, xb, (float*)qwb);
  combine<<<4096, 256, 0, stream>>>(xb, (float*)qwb, vb);
  gemm_bt<1, 64, 64, 512><<<dim3(64, 8), 256, 0, stream>>>(vb, owb, out_b, out, nullptr, nullptr, nullptr,
                                                           4096, 1024, 1024);
}

// Round 18
// 107.779 us; speedup vs baseline: 1.0685x; 1.0685x over previous
//
#include <hip/hip_runtime.h>

// ---------- types ----------
using bh8    = __attribute__((ext_vector_type(8)))  short;          // 8 bf16 (4 VGPR)
using f32x4v = __attribute__((ext_vector_type(4)))  float;
using f32x16 = __attribute__((ext_vector_type(16))) float;
using u32x4  = __attribute__((ext_vector_type(4)))  unsigned int;
using us4    = __attribute__((ext_vector_type(4)))  unsigned short;

#define AS1 __attribute__((address_space(1)))
#define AS3 __attribute__((address_space(3)))

#define B_  2
#define S_  2048
#define D_  1024
#define H_  16
#define HD_ 64
#define C2A 0.0360673760222241f   // 0.2/sqrt(64) * log2(e), folded into Q

__device__ __forceinline__ unsigned short f2bf(float f) {
  unsigned u = __builtin_bit_cast(unsigned, f);
  return (unsigned short)((u + 0x7fffu + ((u >> 16) & 1u)) >> 16);   // RNE
}
__device__ __forceinline__ int swz8(int r) { return (r ^ (r >> 3)) & 7; }

// ---------- fused f32 -> bf16 convert, grid-strided (2048 blocks x 4 iters) ----------
__global__ __launch_bounds__(256) void cvt_all(const float* __restrict__ x,
                                               const float* __restrict__ qw,
                                               const float* __restrict__ ow,
                                               unsigned short* __restrict__ xb,
                                               unsigned short* __restrict__ qwb,
                                               unsigned short* __restrict__ owb) {
#pragma unroll
  for (int it = 0; it < 4; it++) {
    int i = it * 524288 + blockIdx.x * 256 + threadIdx.x;  // vec4 index over 8M floats
    const float* src; unsigned short* dst; int off;
    if (i < 1048576)      { src = x;  dst = xb;  off = i; }
    else if (i < 1835008) { src = qw; dst = qwb; off = i - 1048576; }
    else                  { src = ow; dst = owb; off = i - 1835008; }
    f32x4v v = reinterpret_cast<const f32x4v*>(src)[off];
    us4 o;
    o[0] = f2bf(v[0]); o[1] = f2bf(v[1]); o[2] = f2bf(v[2]); o[3] = f2bf(v[3]);
    reinterpret_cast<us4*>(dst)[off] = o;
  }
}

// ---------- GEMM: C[m,e] = sum_k A[m,k]*B[e,k] (+bias) ----------
// MODE 0: scatter bf16: Q (scaled by C2A) [bh][s][64], K [bh][s][64], V^T [bh][d][S]
// MODE 1: f32 out C[m*N+e] (+bias)
// BM: 128 (waves 2x2, acc[4][4]) or 64 (waves 1x4, acc[4][2])
// GX = gridDim.x, NW = total blocks (both %8 == 0) for bijective XCD swizzle (T1)
template <int MODE, int BM, int GX, int NW>
__global__ __launch_bounds__(256) void gemm_bt(const unsigned short* __restrict__ A,
                                               const unsigned short* __restrict__ Bw,
                                               const float* __restrict__ bias,
                                               float* __restrict__ Cf,
                                               unsigned short* __restrict__ Qo,
                                               unsigned short* __restrict__ Ko,
                                               unsigned short* __restrict__ Vo,
                                               int M, int N, int K) {
  constexpr int NIW = (BM == 128) ? 4 : 2;     // n-frags per wave
  constexpr int NA  = BM / 32;                 // A-staging issues: 256thr*16B = 4KB = 32 rows
  __shared__ __align__(16) short As[BM * 64];
  __shared__ __align__(16) short Bs[128 * 64];
  const int tid = threadIdx.x;
  const int w = tid >> 6, l = tid & 63;
  const int lr = l & 15, lg = l >> 4;
  // XCD swizzle: bijective since NW % 8 == 0
  const int lin = blockIdx.y * GX + blockIdx.x;
  const int sw  = (lin & 7) * (NW / 8) + (lin >> 3);
  const int m0 = (sw % GX) * BM, n0 = (sw / GX) * 128;
  const int wm = (BM == 128) ? (w >> 1) * 64 : 0;
  const int wn = (BM == 128) ? (w & 1) * 64 : w * 32;

  f32x4v acc[4][NIW];
#pragma unroll
  for (int a = 0; a < 4; a++)
#pragma unroll
    for (int b = 0; b < NIW; b++)
#pragma unroll
      for (int r = 0; r < 4; r++) acc[a][b][r] = 0.f;

#pragma unroll 1
  for (int k0 = 0; k0 < K; k0 += 64) {
    __syncthreads();
#pragma unroll
    for (int n = 0; n < NA; n++) {
      int idx = n * 256 + tid;
      int row = idx >> 3, p = idx & 7;
      int c = p ^ swz8(row);
      const unsigned short* srcA = A + (size_t)(m0 + row) * K + k0 + c * 8;
      __builtin_amdgcn_global_load_lds((const AS1 void*)srcA,
          (AS3 void*)((char*)As + (n * 256 + w * 64) * 16), 16, 0, 0);
    }
#pragma unroll
    for (int n = 0; n < 4; n++) {
      int idx = n * 256 + tid;
      int row = idx >> 3, p = idx & 7;
      int c = p ^ swz8(row);
      const unsigned short* srcB = Bw + (size_t)(n0 + row) * K + k0 + c * 8;
      __builtin_amdgcn_global_load_lds((const AS1 void*)srcB,
          (AS3 void*)((char*)Bs + (n * 256 + w * 64) * 16), 16, 0, 0);
    }
    __syncthreads();
#pragma unroll
    for (int kk = 0; kk < 2; kk++) {
      bh8 af[4], bf[NIW];
#pragma unroll
      for (int mi = 0; mi < 4; mi++) {
        int row = wm + mi * 16 + lr;
        int slot = (4 * kk + lg) ^ swz8(row);
        af[mi] = *(const bh8*)((const char*)As + row * 128 + slot * 16);
      }
#pragma unroll
      for (int ni = 0; ni < NIW; ni++) {
        int row = wn + ni * 16 + lr;
        int slot = (4 * kk + lg) ^ swz8(row);
        bf[ni] = *(const bh8*)((const char*)Bs + row * 128 + slot * 16);
      }
#pragma unroll
      for (int mi = 0; mi < 4; mi++)
#pragma unroll
        for (int ni = 0; ni < NIW; ni++)
          acc[mi][ni] = __builtin_amdgcn_mfma_f32_16x16x32_bf16(af[mi], bf[ni], acc[mi][ni], 0, 0, 0);
    }
  }

  // D layout (16x16): col=e=lane&15, row=m=(lane>>4)*4+r  [m89]
  if (MODE == 1) {
#pragma unroll
    for (int ni = 0; ni < NIW; ni++) {
      int e = n0 + wn + ni * 16 + lr;
      float bv = bias[e];
#pragma unroll
      for (int mi = 0; mi < 4; mi++) {
        int mbase = m0 + wm + mi * 16 + lg * 4;
#pragma unroll
        for (int r = 0; r < 4; r++)
          Cf[(size_t)(mbase + r) * N + e] = acc[mi][ni][r] + bv;
      }
    }
  } else {
#pragma unroll
    for (int ni = 0; ni < NIW; ni++) {
      int e = n0 + wn + ni * 16 + lr;
      int hh = e / 192;
      int rr = e - hh * 192;
      int tsel = rr >> 6, d = rr & 63;
      float bv = bias[e];
#pragma unroll
      for (int mi = 0; mi < 4; mi++) {
        int mbase = m0 + wm + mi * 16 + lg * 4;
#pragma unroll
        for (int r = 0; r < 4; r++) {
          int m = mbase + r;
          int b = m >> 11, s = m & 2047;
          float val = acc[mi][ni][r] + bv;
          size_t bh = (size_t)(b * H_ + hh);
          if (tsel == 0)      Qo[(bh * S_ + s) * HD_ + d] = f2bf(val * C2A);
          else if (tsel == 1) Ko[(bh * S_ + s) * HD_ + d] = f2bf(val);
          else                Vo[(bh * HD_ + d) * S_ + s] = f2bf(val);   // V^T
        }
      }
    }
  }
}

// ---------- fused attention (R11/R14/R16-verified, byte-for-byte) ----------
// grid 256 (XCD-swizzled), 512 thr = 8 waves, each wave owns 32 q-rows and
// iterates ALL t. 256 t-rows per barrier (four 64-t tiles staged per iter,
// 8 global_load_lds/thread, 128KB dbuf LDS): 8 barriers total.
__global__ __launch_bounds__(512) void attn_fwd(const unsigned short* __restrict__ Qt,
                                                const unsigned short* __restrict__ Kt,
                                                const unsigned short* __restrict__ VT,
                                                unsigned short* __restrict__ vals) {
  __shared__ __align__(16) short Ks[2 * 4 * 64 * 64];   // [buf][tile][64][64] 64KB
  __shared__ __align__(16) short Vs[2 * 4 * 64 * 64];   // 64KB
  const int tid = threadIdx.x, w = tid >> 6, l = tid & 63;
  const int lq = l & 31, h = l >> 5;
  // XCD swizzle: all 8 q-blocks of a (b,h) land on one XCD (same lin%8)
  const int lin = blockIdx.x;
  const int uu_ = lin >> 3;
  const int bh = (lin & 7) + 8 * (uu_ & 3);
  const int q0 = (uu_ >> 2) * 256 + w * 32;
  const unsigned short* Qp = Qt + (size_t)bh * (S_ * HD_);
  const unsigned short* Kp = Kt + (size_t)bh * (S_ * HD_);
  const unsigned short* Vp = VT + (size_t)bh * (HD_ * S_);

  bh8 qf[4];  // B-frags: col=q=lane&31, k=d=(lane>>5)*8+j
#pragma unroll
  for (int kf = 0; kf < 4; kf++)
    qf[kf] = *(const bh8*)(Qp + (size_t)(q0 + lq) * HD_ + kf * 16 + h * 8);

  // persistent zero C-operand
  f32x16 KZ;
#pragma unroll
  for (int r = 0; r < 16; r++) KZ[r] = 0.f;
  bh8 ones;
#pragma unroll
  for (int j = 0; j < 8; j++) ones[j] = (short)0x3F80;

  f32x16 O[2], Ol;
  O[0] = KZ; O[1] = KZ; Ol = KZ;

  // per-thread staging addresses (512 threads cover one 64x64 tile per issue)
  const int row0 = tid >> 3, cc = (tid & 7) ^ swz8(row0);
  const unsigned short* kp0 = Kp + row0 * HD_ + cc * 8;
  const unsigned short* vp0 = Vp + (size_t)row0 * S_ + cc * 8;
  char* dK = (char*)Ks + w * 1024;
  char* dV = (char*)Vs + w * 1024;

  // i indexes 256-t super-tiles; tiles at t = 256i + 64j, j=0..3
  auto stage = [&](int i, int buf) {
    const unsigned short* kB = kp0 + (size_t)i * 16384;  // 256 rows * 64 elems
    const unsigned short* vB = vp0 + (size_t)i * 256;    // V^T: +256 t-elems
#pragma unroll
    for (int j = 0; j < 4; j++) {
      __builtin_amdgcn_global_load_lds((const AS1 void*)(kB + j * 4096),
                                       (AS3 void*)(dK + buf * 32768 + j * 8192), 16, 0, 0);
      __builtin_amdgcn_global_load_lds((const AS1 void*)(vB + j * 64),
                                       (AS3 void*)(dV + buf * 32768 + j * 8192), 16, 0, 0);
    }
  };

  // LDS read byte-offsets within a 64x64 tile (loop-invariant)
  int ko0[4], ko1[4], vo0[4], vo1[4];
#pragma unroll
  for (int kf = 0; kf < 4; kf++) {
    int r0 = lq, r1 = 32 + lq;
    ko0[kf] = r0 * 128 + (((2 * kf + h) ^ swz8(r0)) << 4);
    ko1[kf] = r1 * 128 + (((2 * kf + h) ^ swz8(r1)) << 4);
  }
#pragma unroll
  for (int c = 0; c < 2; c++)
#pragma unroll
    for (int ni = 0; ni < 2; ni++) {
      int d = ni * 32 + lq;
      vo0[c * 2 + ni] = d * 128 + (((2 * c + h) ^ swz8(d)) << 4);
      vo1[c * 2 + ni] = d * 128 + (((4 + 2 * c + h) ^ swz8(d)) << 4);
    }

  stage(0, 0);
#pragma unroll 1
  for (int i = 0; i < 8; i++) {
    const int cur = i & 1;
    asm volatile("s_waitcnt vmcnt(0)" ::: "memory");   // my tile-i staging done
    __builtin_amdgcn_s_barrier();                      // everyone staged; prev-buf readers done
    if (i < 7) stage(i + 1, cur ^ 1);                  // prefetch flies under compute
#pragma unroll
    for (int tt = 0; tt < 4; tt++) {
      const char* Kc = (const char*)Ks + cur * 32768 + tt * 8192;
      const char* Vc = (const char*)Vs + cur * 32768 + tt * 8192;

      // ---- QK^T, both 32-t sub-tiles ----
      f32x16 sa, sb;
      __builtin_amdgcn_s_setprio(1);
      {
        bh8 k0 = *(const bh8*)(Kc + ko0[0]);
        bh8 k1 = *(const bh8*)(Kc + ko1[0]);
        sa = __builtin_amdgcn_mfma_f32_32x32x16_bf16(k0, qf[0], KZ, 0, 0, 0);
        sb = __builtin_amdgcn_mfma_f32_32x32x16_bf16(k1, qf[0], KZ, 0, 0, 0);
      }
#pragma unroll
      for (int kf = 1; kf < 4; kf++) {
        bh8 k0 = *(const bh8*)(Kc + ko0[kf]);
        bh8 k1 = *(const bh8*)(Kc + ko1[kf]);
        sa = __builtin_amdgcn_mfma_f32_32x32x16_bf16(k0, qf[kf], sa, 0, 0, 0);
        sb = __builtin_amdgcn_mfma_f32_32x32x16_bf16(k1, qf[kf], sb, 0, 0, 0);
      }
      __builtin_amdgcn_s_setprio(0);

      // ---- softmax numerators, chain a then chain b ----
      float pa_[16], pb_[16];
#pragma unroll
      for (int r = 0; r < 16; r++)
        asm("v_exp_f32 %0, %1" : "=v"(pa_[r]) : "v"(sa[r]));
      unsigned wa0[4], wa1[4];
#pragma unroll
      for (int g = 0; g < 4; g++) {
        asm("v_cvt_pk_bf16_f32 %0, %1, %2" : "=v"(wa0[g]) : "v"(pa_[4 * g]), "v"(pa_[4 * g + 1]));
        asm("v_cvt_pk_bf16_f32 %0, %1, %2" : "=v"(wa1[g]) : "v"(pa_[4 * g + 2]), "v"(pa_[4 * g + 3]));
      }
#pragma unroll
      for (int r = 0; r < 16; r++)
        asm("v_exp_f32 %0, %1" : "=v"(pb_[r]) : "v"(sb[r]));
      unsigned wb0[4], wb1[4];
#pragma unroll
      for (int g = 0; g < 4; g++) {
        asm("v_cvt_pk_bf16_f32 %0, %1, %2" : "=v"(wb0[g]) : "v"(pb_[4 * g]), "v"(pb_[4 * g + 1]));
        asm("v_cvt_pk_bf16_f32 %0, %1, %2" : "=v"(wb1[g]) : "v"(pb_[4 * g + 2]), "v"(pb_[4 * g + 3]));
      }

      // ---- rebuild PV A-frags via permlane32_swap (T12) ----
      bh8 paf[2], pbf[2];
#pragma unroll
      for (int c = 0; c < 2; c++) {
        unsigned x0 = wa0[2 * c], y0 = wa0[2 * c + 1];
        unsigned x1 = wa1[2 * c], y1 = wa1[2 * c + 1];
        asm("v_permlane32_swap_b32 %0, %1" : "+v"(x0), "+v"(y0));
        asm("v_permlane32_swap_b32 %0, %1" : "+v"(x1), "+v"(y1));
        u32x4 up; up[0] = x0; up[1] = x1; up[2] = y0; up[3] = y1;
        paf[c] = __builtin_bit_cast(bh8, up);
      }
#pragma unroll
      for (int c = 0; c < 2; c++) {
        unsigned x0 = wb0[2 * c], y0 = wb0[2 * c + 1];
        unsigned x1 = wb1[2 * c], y1 = wb1[2 * c + 1];
        asm("v_permlane32_swap_b32 %0, %1" : "+v"(x0), "+v"(y0));
        asm("v_permlane32_swap_b32 %0, %1" : "+v"(x1), "+v"(y1));
        u32x4 up; up[0] = x0; up[1] = x1; up[2] = y0; up[3] = y1;
        pbf[c] = __builtin_bit_cast(bh8, up);
      }

      // ---- PV + L, both chains ----
      __builtin_amdgcn_s_setprio(1);
#pragma unroll
      for (int c = 0; c < 2; c++) {
        bh8 vf0 = *(const bh8*)(Vc + vo0[c * 2 + 0]);
        bh8 vf1 = *(const bh8*)(Vc + vo0[c * 2 + 1]);
        O[0] = __builtin_amdgcn_mfma_f32_32x32x16_bf16(paf[c], vf0, O[0], 0, 0, 0);
        O[1] = __builtin_amdgcn_mfma_f32_32x32x16_bf16(paf[c], vf1, O[1], 0, 0, 0);
        Ol   = __builtin_amdgcn_mfma_f32_32x32x16_bf16(paf[c], ones, Ol, 0, 0, 0);
      }
#pragma unroll
      for (int c = 0; c < 2; c++) {
        bh8 vf0 = *(const bh8*)(Vc + vo1[c * 2 + 0]);
        bh8 vf1 = *(const bh8*)(Vc + vo1[c * 2 + 1]);
        O[0] = __builtin_amdgcn_mfma_f32_32x32x16_bf16(pbf[c], vf0, O[0], 0, 0, 0);
        O[1] = __builtin_amdgcn_mfma_f32_32x32x16_bf16(pbf[c], vf1, O[1], 0, 0, 0);
        Ol   = __builtin_amdgcn_mfma_f32_32x32x16_bf16(pbf[c], ones, Ol, 0, 0, 0);
      }
      __builtin_amdgcn_s_setprio(0);
    }
  }

  // denominators already in Ol[r] = L[q_r] (replicated across lanes)
  float rl[16];
#pragma unroll
  for (int r = 0; r < 16; r++) rl[r] = __builtin_amdgcn_rcpf(Ol[r]);

  const int b = bh >> 4, hh = bh & 15;
#pragma unroll
  for (int ni = 0; ni < 2; ni++) {
    int d = ni * 32 + lq;
#pragma unroll
    for (int r = 0; r < 16; r++) {
      float vvv = O[ni][r] * rl[r];
      int qg = q0 + 4 * h + 8 * (r >> 2) + (r & 3);
      vals[((size_t)(b * S_ + qg)) * D_ + hh * HD_ + d] = f2bf(vvv);
    }
  }
}

// ---------- launch ----------
extern "C" void kernel_launch(void* const* d_in, const int* in_sizes, int n_in,
                              void* d_out, int out_size, void* d_ws, size_t ws_size,
                              hipStream_t stream) {
  const float* x     = (const float*)d_in[0];
  const float* qkv_w = (const float*)d_in[1];
  const float* qkv_b = (const float*)d_in[2];
  const float* out_w = (const float*)d_in[3];
  const float* out_b = (const float*)d_in[4];
  float* out = (float*)d_out;

  unsigned short* xb  = (unsigned short*)d_ws;                 // 8 MB  x bf16 [4096][1024]
  unsigned short* qwb = xb  + (size_t)4096 * 1024;             // 6 MB  qkv_w bf16
  unsigned short* owb = qwb + (size_t)3072 * 1024;             // 2 MB  out_w bf16
  unsigned short* Qb  = owb + (size_t)1024 * 1024;             // 8 MB  Q*C2 [32][2048][64]
  unsigned short* Kb  = Qb  + (size_t)32 * 2048 * 64;          // 8 MB  K [32][2048][64]
  unsigned short* Vb  = Kb  + (size_t)32 * 2048 * 64;          // 8 MB  V^T [32][64][2048]
  unsigned short* vb  = Vb  + (size_t)32 * 2048 * 64;          // 8 MB  vals bf16

  cvt_all<<<2048, 256, 0, stream>>>(x, qkv_w, out_w, xb, qwb, owb);
  gemm_bt<0, 128, 32, 768><<<dim3(32, 24), 256, 0, stream>>>(xb, qwb, qkv_b, nullptr, Qb, Kb, Vb,
                                                             4096, 3072, 1024);
  attn_fwd<<<256, 512, 0, stream>>>(Qb, Kb, Vb, vb);
  gemm_bt<1, 64, 64, 512><<<dim3(64, 8), 256, 0, stream>>>(vb, owb, out_b, out, nullptr, nullptr, nullptr,
                                                           4096, 1024, 1024);
}